// Round 6
// baseline (79.427 us; speedup 1.0000x reference)
//
#include <hip/hip_runtime.h>
#include <math.h>

#define NB 4096

#define SCALE_POS 2.0f
#define SCALE_NEG 50.0f
#define THRESH    0.7f
#define MARGIN    0.1f
#define GAMMA     0.3f
#define EPS_SELF  1e-5f

typedef __attribute__((ext_vector_type(8))) short s16x8;
typedef __attribute__((ext_vector_type(16))) float f32x16;
typedef unsigned long long u64;
typedef unsigned int u32;
typedef unsigned char u8;

// Monotone float<->uint key (order-preserving incl +-inf)
__device__ __forceinline__ u32 fkey(float f) {
  u32 u = __float_as_uint(f);
  return (u & 0x80000000u) ? ~u : (u | 0x80000000u);
}
__device__ __forceinline__ float keyf(u32 k) {
  u32 u = (k & 0x80000000u) ? (k & 0x7FFFFFFFu) : ~k;
  return __uint_as_float(u);
}
__device__ __forceinline__ short f2bf(float x) {  // RNE to bf16
  u32 u = __float_as_uint(x);
  return (short)((u + 0x7FFFu + ((u >> 16) & 1u)) >> 16);
}
__device__ __forceinline__ float bf2f(short h) {
  return __uint_as_float(((u32)(unsigned short)h) << 16);
}

// ---------------------------------------------------------------------------
// K1: fp32 -> split-bf16 into fragment-major F layout for 32x32x16 MFMA.
// Fragment (T32, s): lane l holds row T32*32+(l&31), k = s*16+(l>>5)*8..+8.
// s16x8 index: hi at (T32*16+s)*64+l, lo at (T32*16+8+s)*64+l. Writes coalesced.
__global__ __launch_bounds__(256) void k1_convert(
    const float* __restrict__ emb, const int* __restrict__ labels,
    short* __restrict__ F, u8* __restrict__ labu8,
    u64* __restrict__ minkey, u32* __restrict__ maxkey) {
  int t = blockIdx.x * 256 + threadIdx.x;  // 0..65535
  int T = t >> 9, s = (t >> 6) & 7, l = t & 63;
  int row = T * 32 + (l & 31);
  int c4 = s * 4 + (l >> 5) * 2;  // float4 index of this 8-float chunk
  const float4* e4 = (const float4*)emb;
  float4 v0 = e4[row * 32 + c4];
  float4 v1 = e4[row * 32 + c4 + 1];
  float xs[8] = {v0.x, v0.y, v0.z, v0.w, v1.x, v1.y, v1.z, v1.w};
  s16x8 h, lo;
#pragma unroll
  for (int e = 0; e < 8; ++e) {
    short hh = f2bf(xs[e]);
    h[e] = hh;
    lo[e] = f2bf(xs[e] - bf2f(hh));
  }
  ((s16x8*)F)[(T * 16 + s) * 64 + l] = h;
  ((s16x8*)F)[(T * 16 + 8 + s) * 64 + l] = lo;
  if (t < 1024) {
    int4 lb = ((const int4*)labels)[t];
    uchar4 p;
    p.x = (u8)lb.x; p.y = (u8)lb.y; p.z = (u8)lb.z; p.w = (u8)lb.w;
    ((uchar4*)labu8)[t] = p;
  }
  if (t < NB) {
    minkey[t] = 0xFF800000FFFFFFFFULL;  // (+inf key, idx ~0)
    maxkey[t] = 0x007FFFFFu;            // -inf key
  }
}

// ---------------------------------------------------------------------------
// K2 (pass 1): Gram via 32x32x16 split-bf16 MFMA, no LDS, coalesced 1KB
// fragment loads from L2. Wave tile 64x64 (2x2 tiles, acc 4x f32x16 = 64 regs).
// __launch_bounds__(256,4) caps regs at 128 -> 4 waves/SIMD.
// Stores sim bf16 (64B segments) + register mining -> atomics. grid (32,32).
__global__ __launch_bounds__(256, 4) void k2_pass1(
    const short* __restrict__ F, const int* __restrict__ labels,
    short* __restrict__ simh,
    u64* __restrict__ minkey, u32* __restrict__ maxkey) {
  int tid = threadIdx.x, w = tid >> 6, l = tid & 63;
  int lo5 = l & 31, hi = l >> 5;
  int mt0 = blockIdx.y * 4 + (w >> 1) * 2;  // 32-row tile idx
  int nt0 = blockIdx.x * 4 + (w & 1) * 2;
  const s16x8* F8 = (const s16x8*)F;

  f32x16 acc[2][2] = {};
#pragma unroll 1
  for (int s = 0; s < 8; ++s) {
    s16x8 ah[2], al[2], bh[2], bl[2];
#pragma unroll
    for (int t = 0; t < 2; ++t) {
      int ia = ((mt0 + t) * 16 + s) * 64 + l;
      int ib = ((nt0 + t) * 16 + s) * 64 + l;
      ah[t] = F8[ia]; al[t] = F8[ia + 512];  // lo plane: +8*64
      bh[t] = F8[ib]; bl[t] = F8[ib + 512];
    }
#pragma unroll
    for (int ti = 0; ti < 2; ++ti)
#pragma unroll
      for (int tj = 0; tj < 2; ++tj) {
        acc[ti][tj] = __builtin_amdgcn_mfma_f32_32x32x16_bf16(ah[ti], bh[tj], acc[ti][tj], 0, 0, 0);
        acc[ti][tj] = __builtin_amdgcn_mfma_f32_32x32x16_bf16(ah[ti], bl[tj], acc[ti][tj], 0, 0, 0);
        acc[ti][tj] = __builtin_amdgcn_mfma_f32_32x32x16_bf16(al[ti], bh[tj], acc[ti][tj], 0, 0, 0);
      }
  }

  int labn[2];
#pragma unroll
  for (int tj = 0; tj < 2; ++tj) labn[tj] = labels[(nt0 + tj) * 32 + lo5];

#pragma unroll
  for (int ti = 0; ti < 2; ++ti) {
#pragma unroll
    for (int q = 0; q < 4; ++q) {
      // labels for rows m = (mt0+ti)*32 + q*8 + hi*4 + rr, rr=0..3
      int4 lm4 = ((const int4*)labels)[(mt0 + ti) * 8 + q * 2 + hi];
#pragma unroll
      for (int rr = 0; rr < 4; ++rr) {
        const int reg = q * 4 + rr;
        int m = (mt0 + ti) * 32 + q * 8 + hi * 4 + rr;
        int lm = ((const int*)&lm4)[rr];
        u64 pk = 0xFF800000FFFFFFFFULL;
        u32 nk = 0x007FFFFFu;
#pragma unroll
        for (int tj = 0; tj < 2; ++tj) {
          float sv = acc[ti][tj][reg];
          int n = (nt0 + tj) * 32 + lo5;
          if (n == m) sv = 1.0f;  // exact diagonal; excluded by value gate
          simh[(size_t)m * NB + n] = f2bf(sv);
          if (lm == labn[tj]) {
            if (sv < 1.0f - EPS_SELF) {
              u64 cand = ((u64)fkey(sv) << 32) | (u32)n;
              pk = pk < cand ? pk : cand;
            }
          } else {
            u32 ck = fkey(sv);
            nk = nk > ck ? nk : ck;
          }
        }
#pragma unroll
        for (int d = 1; d < 32; d <<= 1) {  // reduce over 32 lanes (same hi)
          u64 po = __shfl_xor(pk, d, 64); pk = pk < po ? pk : po;
          u32 no = __shfl_xor(nk, d, 64); nk = nk > no ? nk : no;
        }
        if (lo5 == 0) {
          atomicMin(&minkey[m], pk);
          atomicMax(&maxkey[m], nk);
        }
      }
    }
  }
}

// ---------------------------------------------------------------------------
// K3: decode keys -> row params (identities from unit-norm rows).
__global__ __launch_bounds__(256) void k3_prep(
    const u64* __restrict__ minkey, const u32* __restrict__ maxkey,
    float* __restrict__ minposf, float* __restrict__ maxnegf,
    float* __restrict__ dppA, float* __restrict__ inppA,
    int* __restrict__ jarr, int* __restrict__ validA) {
  int i = blockIdx.x * 256 + threadIdx.x;
  u64 mk = minkey[i];
  float minpos = keyf((u32)(mk >> 32));
  float maxneg = keyf(maxkey[i]);
  bool valid = (maxneg + MARGIN > minpos);
  int j = valid ? (int)(mk & 0xFFFFFFFFu) : i;
  minposf[i] = minpos;
  maxnegf[i] = maxneg;
  dppA[i] = minpos - 1.0f;  // e_i.d_p = sim_ij - 1
  inppA[i] = 1.0f / fmaxf(sqrtf(fmaxf(2.0f - 2.0f * minpos, 1e-12f)), 1e-8f);
  jarr[i] = j;
  validA[i] = valid ? 1 : 0;
}

// ---------------------------------------------------------------------------
// K4: per-anchor streaming pass over bf16 sim[i,:], sim[j,:] + u8 labels.
__global__ __launch_bounds__(256) void k4_row(
    const short* __restrict__ simh, const u8* __restrict__ labu8,
    const float* __restrict__ minposf, const float* __restrict__ maxnegf,
    const float* __restrict__ dppA, const float* __restrict__ inppA,
    const int* __restrict__ jarr, const int* __restrict__ validA,
    float* __restrict__ rowloss) {
  int i = blockIdx.x, tid = threadIdx.x;
  if (!validA[i]) {
    if (tid == 0) rowloss[i] = 0.0f;
    return;
  }
  int j = jarr[i];
  float mp = minposf[i], mx = maxnegf[i];
  float dpp = dppA[i], inpp = inppA[i];
  int lm = (int)labu8[i];
  const s16x8* sI = (const s16x8*)(simh + (size_t)i * NB);
  const s16x8* sJ = (const s16x8*)(simh + (size_t)j * NB);
  const u64* L8 = (const u64*)labu8;
  float ps = 0.0f, ns = 0.0f;
#pragma unroll 1
  for (int c = tid; c < NB / 8; c += 256) {  // 2 iterations
    s16x8 a = sI[c];
    s16x8 b = sJ[c];
    u64 lab = L8[c];
#pragma unroll
    for (int e = 0; e < 8; ++e) {
      float s = bf2f(a[e]);
      int ln = (int)((lab >> (8 * e)) & 255u);
      if (ln == lm) {
        if (s < 1.0f - EPS_SELF && s - MARGIN < mx)
          ps += __expf(-SCALE_POS * (s - THRESH));
      } else if (s + MARGIN > mp) {
        float sj = bf2f(b[e]);
        float nn = fmaxf(sqrtf(fmaxf(2.0f - 2.0f * s, 1e-12f)), 1e-8f);
        float rg = GAMMA * (sj - s - dpp) * inpp * __builtin_amdgcn_rcpf(nn);
        ns += __expf(SCALE_NEG * (s - THRESH - rg));
      }
    }
  }
#pragma unroll
  for (int d = 1; d < 64; d <<= 1) {
    ps += __shfl_xor(ps, d, 64);
    ns += __shfl_xor(ns, d, 64);
  }
  __shared__ float redp[4], redn[4];
  if ((tid & 63) == 0) {
    redp[tid >> 6] = ps;
    redn[tid >> 6] = ns;
  }
  __syncthreads();
  if (tid == 0) {
    float tp = redp[0] + redp[1] + redp[2] + redp[3];
    float tn = redn[0] + redn[1] + redn[2] + redn[3];
    rowloss[i] = log1pf(tp) * (1.0f / SCALE_POS) + log1pf(tn) * (1.0f / SCALE_NEG);
  }
}

// ---------------------------------------------------------------------------
// K5: mean over rows. Single block.
__global__ __launch_bounds__(1024) void k5_final(
    const float* __restrict__ rowloss, float* __restrict__ out) {
  int tid = threadIdx.x;
  float local = 0.0f;
  for (int r = tid; r < NB; r += 1024) local += rowloss[r];
#pragma unroll
  for (int d = 1; d < 64; d <<= 1) local += __shfl_xor(local, d, 64);
  __shared__ float partial[16];
  if ((tid & 63) == 0) partial[tid >> 6] = local;
  __syncthreads();
  if (tid == 0) {
    float t = 0.0f;
#pragma unroll
    for (int q = 0; q < 16; ++q) t += partial[q];
    out[0] = t / (float)NB;
  }
}

// ---------------------------------------------------------------------------
extern "C" void kernel_launch(void* const* d_in, const int* in_sizes, int n_in,
                              void* d_out, int out_size, void* d_ws, size_t ws_size,
                              hipStream_t stream) {
  const float* emb = (const float*)d_in[0];
  const int* labels = (const int*)d_in[1];
  float* out = (float*)d_out;
  char* ws = (char*)d_ws;

  short* simh = (short*)ws;                               // 32 MB bf16 sim
  short* F = (short*)(ws + ((size_t)NB * NB * 2));        // 2 MB split-bf16 frags
  char* base = ws + ((size_t)NB * NB * 2) + (2 << 20);
  u64* minkey = (u64*)(base);                             // 32 KB
  u32* maxkey = (u32*)(base + 32768);                     // 16 KB
  float* minposf = (float*)(base + 49152);
  float* maxnegf = (float*)(base + 65536);
  float* dppA = (float*)(base + 81920);
  float* inppA = (float*)(base + 98304);
  int* jarr = (int*)(base + 114688);
  int* validA = (int*)(base + 131072);
  float* rowloss = (float*)(base + 147456);
  u8* labu8 = (u8*)(base + 163840);                       // 4 KB

  hipLaunchKernelGGL(k1_convert, dim3(256), dim3(256), 0, stream,
                     emb, labels, F, labu8, minkey, maxkey);
  hipLaunchKernelGGL(k2_pass1, dim3(NB / 128, NB / 128), dim3(256), 0, stream,
                     F, labels, simh, minkey, maxkey);
  hipLaunchKernelGGL(k3_prep, dim3(NB / 256), dim3(256), 0, stream,
                     minkey, maxkey, minposf, maxnegf, dppA, inppA, jarr, validA);
  hipLaunchKernelGGL(k4_row, dim3(NB), dim3(256), 0, stream,
                     simh, labu8, minposf, maxnegf, dppA, inppA, jarr, validA, rowloss);
  hipLaunchKernelGGL(k5_final, dim3(1), dim3(1024), 0, stream, rowloss, out);
}

// Round 7
// 56.134 us; speedup vs baseline: 1.4150x; 1.4150x over previous
//
#include <hip/hip_runtime.h>
#include <math.h>

#define NB 4096

#define SCALE_POS 2.0f
#define SCALE_NEG 50.0f
#define THRESH    0.7f
#define MARGIN    0.1f
#define GAMMA     0.3f
#define EPS_SELF  1e-5f

typedef __attribute__((ext_vector_type(8))) short s16x8;
typedef __attribute__((ext_vector_type(16))) float f32x16;
typedef unsigned long long u64;
typedef unsigned int u32;
typedef unsigned char u8;

__device__ __forceinline__ short f2bf(float x) {  // RNE to bf16
  u32 u = __float_as_uint(x);
  return (short)((u + 0x7FFFu + ((u >> 16) & 1u)) >> 16);
}
__device__ __forceinline__ float bf2f(short h) {
  return __uint_as_float(((u32)(unsigned short)h) << 16);
}
// Monotone 16-bit key for bf16 bit patterns (order-preserving)
__device__ __forceinline__ u32 mono16(u32 h) {
  return (h & 0x8000u) ? (h ^ 0xFFFFu) : (h | 0x8000u);
}
__device__ __forceinline__ float unmono16(u32 m) {
  u32 h = (m & 0x8000u) ? (m & 0x7FFFu) : (~m & 0xFFFFu);
  return bf2f((short)h);
}

// ---------------------------------------------------------------------------
// K1: fp32 -> split-bf16 into fragment-major F layout for 32x32x16 MFMA;
// pack labels to u8. Fragment (T32,s): lane l holds row T32*32+(l&31),
// k = s*16+(l>>5)*8..+8. hi at (T32*16+s)*64+l, lo at (T32*16+8+s)*64+l.
__global__ __launch_bounds__(256) void k1_convert(
    const float* __restrict__ emb, const int* __restrict__ labels,
    short* __restrict__ F, u8* __restrict__ labu8) {
  int t = blockIdx.x * 256 + threadIdx.x;  // 0..65535
  int T = t >> 9, s = (t >> 6) & 7, l = t & 63;
  int row = T * 32 + (l & 31);
  int c4 = s * 4 + (l >> 5) * 2;  // float4 index of this 8-float chunk
  const float4* e4 = (const float4*)emb;
  float4 v0 = e4[row * 32 + c4];
  float4 v1 = e4[row * 32 + c4 + 1];
  float xs[8] = {v0.x, v0.y, v0.z, v0.w, v1.x, v1.y, v1.z, v1.w};
  s16x8 h, lo;
#pragma unroll
  for (int e = 0; e < 8; ++e) {
    short hh = f2bf(xs[e]);
    h[e] = hh;
    lo[e] = f2bf(xs[e] - bf2f(hh));
  }
  ((s16x8*)F)[(T * 16 + s) * 64 + l] = h;
  ((s16x8*)F)[(T * 16 + 8 + s) * 64 + l] = lo;
  if (t < 1024) {
    int4 lb = ((const int4*)labels)[t];
    uchar4 p;
    p.x = (u8)lb.x; p.y = (u8)lb.y; p.z = (u8)lb.z; p.w = (u8)lb.w;
    ((uchar4*)labu8)[t] = p;
  }
}

// ---------------------------------------------------------------------------
// K2: PURE Gram GEMM via 32x32x16 split-bf16 MFMA -> bf16 sim store.
// No labels, no mining, no atomics, no shuffles. Wave tile 64x64 (2x2 tiles),
// coalesced 1KB fragment loads from L2, 64B-contiguous stores. grid (32,32).
__global__ __launch_bounds__(256, 4) void k2_pass1(
    const short* __restrict__ F, short* __restrict__ simh) {
  int tid = threadIdx.x, w = tid >> 6, l = tid & 63;
  int lo5 = l & 31, hi = l >> 5;
  int mt0 = blockIdx.y * 4 + (w >> 1) * 2;  // 32-row tile idx
  int nt0 = blockIdx.x * 4 + (w & 1) * 2;
  const s16x8* F8 = (const s16x8*)F;

  f32x16 acc[2][2] = {};
#pragma unroll 1
  for (int s = 0; s < 8; ++s) {
    s16x8 ah[2], al[2], bh[2], bl[2];
#pragma unroll
    for (int t = 0; t < 2; ++t) {
      int ia = ((mt0 + t) * 16 + s) * 64 + l;
      int ib = ((nt0 + t) * 16 + s) * 64 + l;
      ah[t] = F8[ia]; al[t] = F8[ia + 512];  // lo plane: +8*64
      bh[t] = F8[ib]; bl[t] = F8[ib + 512];
    }
#pragma unroll
    for (int ti = 0; ti < 2; ++ti)
#pragma unroll
      for (int tj = 0; tj < 2; ++tj) {
        acc[ti][tj] = __builtin_amdgcn_mfma_f32_32x32x16_bf16(ah[ti], bh[tj], acc[ti][tj], 0, 0, 0);
        acc[ti][tj] = __builtin_amdgcn_mfma_f32_32x32x16_bf16(ah[ti], bl[tj], acc[ti][tj], 0, 0, 0);
        acc[ti][tj] = __builtin_amdgcn_mfma_f32_32x32x16_bf16(al[ti], bh[tj], acc[ti][tj], 0, 0, 0);
      }
  }

#pragma unroll
  for (int ti = 0; ti < 2; ++ti)
#pragma unroll
    for (int tj = 0; tj < 2; ++tj) {
      int n = (nt0 + tj) * 32 + lo5;
#pragma unroll
      for (int q = 0; q < 4; ++q)
#pragma unroll
        for (int rr = 0; rr < 4; ++rr) {
          int m = (mt0 + ti) * 32 + q * 8 + hi * 4 + rr;
          simh[(size_t)m * NB + n] = f2bf(acc[ti][tj][q * 4 + rr]);
        }
    }
}

// ---------------------------------------------------------------------------
// K4: per-anchor fused mine + loss. One block per row i.
// Phase 1: mine min-pos(+argmin)/max-neg on bf16 sim[i,:] with u32 packed keys
// (sim[i,:] and labels kept in registers). Phase 2: stream sim[j,:] only.
__global__ __launch_bounds__(256) void k4_row(
    const short* __restrict__ simh, const u8* __restrict__ labu8,
    float* __restrict__ rowloss) {
  int i = blockIdx.x, tid = threadIdx.x;
  int lm = (int)labu8[i];
  const s16x8* sI = (const s16x8*)(simh + (size_t)i * NB);
  const u64* L8 = (const u64*)labu8;
  s16x8 a0 = sI[tid], a1 = sI[tid + 256];
  u64 lb0 = L8[tid], lb1 = L8[tid + 256];

  u32 pk = 0xFFFFFFFFu;  // min over (mono16(bf16)<<16 | n)
  u32 nk = 0u;           // max over same packing
  {
    s16x8 aa[2] = {a0, a1};
    u64 ll[2] = {lb0, lb1};
#pragma unroll
    for (int c = 0; c < 2; ++c) {
      int nbase = (tid + c * 256) * 8;
#pragma unroll
      for (int e = 0; e < 8; ++e) {
        u32 h = (u32)(unsigned short)aa[c][e];
        u32 key = (mono16(h) << 16) | (u32)(nbase + e);
        int ln = (int)((ll[c] >> (8 * e)) & 255u);
        float s = bf2f((short)h);
        if (ln == lm) {
          if (s < 1.0f - EPS_SELF) pk = pk < key ? pk : key;
        } else {
          nk = nk > key ? nk : key;
        }
      }
    }
  }
#pragma unroll
  for (int d = 1; d < 64; d <<= 1) {
    u32 po = __shfl_xor(pk, d, 64); pk = pk < po ? pk : po;
    u32 no = __shfl_xor(nk, d, 64); nk = nk > no ? nk : no;
  }
  __shared__ u32 spk[4], snk[4];
  __shared__ float s_mp, s_mx, s_dpp, s_inpp;
  __shared__ int s_j, s_valid;
  if ((tid & 63) == 0) { spk[tid >> 6] = pk; snk[tid >> 6] = nk; }
  __syncthreads();
  if (tid == 0) {
    u32 P = spk[0], N = snk[0];
#pragma unroll
    for (int q = 1; q < 4; ++q) {
      P = P < spk[q] ? P : spk[q];
      N = N > snk[q] ? N : snk[q];
    }
    float minpos = unmono16(P >> 16);   // NaN if no positive
    float maxneg = unmono16(N >> 16);   // NaN if no negative
    bool valid = (maxneg + MARGIN > minpos);
    s_valid = valid ? 1 : 0;
    s_j = valid ? (int)(P & 0xFFFFu) : i;
    s_mp = minpos;
    s_mx = maxneg;
    s_dpp = minpos - 1.0f;  // e_i.d_p = sim_ij - 1 (unit rows)
    s_inpp = 1.0f / fmaxf(sqrtf(fmaxf(2.0f - 2.0f * minpos, 1e-12f)), 1e-8f);
  }
  __syncthreads();
  if (!s_valid) {
    if (tid == 0) rowloss[i] = 0.0f;
    return;
  }
  float mp = s_mp, mx = s_mx, dpp = s_dpp, inpp = s_inpp;
  const s16x8* sJ = (const s16x8*)(simh + (size_t)s_j * NB);
  s16x8 b0 = sJ[tid], b1 = sJ[tid + 256];

  float ps = 0.0f, ns = 0.0f;
  {
    s16x8 aa[2] = {a0, a1};
    s16x8 bb[2] = {b0, b1};
    u64 ll[2] = {lb0, lb1};
#pragma unroll
    for (int c = 0; c < 2; ++c) {
#pragma unroll
      for (int e = 0; e < 8; ++e) {
        float s = bf2f(aa[c][e]);
        int ln = (int)((ll[c] >> (8 * e)) & 255u);
        if (ln == lm) {
          if (s < 1.0f - EPS_SELF && s - MARGIN < mx)
            ps += __expf(-SCALE_POS * (s - THRESH));
        } else if (s + MARGIN > mp) {
          float sjv = bf2f(bb[c][e]);
          float nn = fmaxf(sqrtf(fmaxf(2.0f - 2.0f * s, 1e-12f)), 1e-8f);
          float rg = GAMMA * (sjv - s - dpp) * inpp * __builtin_amdgcn_rcpf(nn);
          ns += __expf(SCALE_NEG * (s - THRESH - rg));
        }
      }
    }
  }
#pragma unroll
  for (int d = 1; d < 64; d <<= 1) {
    ps += __shfl_xor(ps, d, 64);
    ns += __shfl_xor(ns, d, 64);
  }
  __shared__ float redp[4], redn[4];
  if ((tid & 63) == 0) {
    redp[tid >> 6] = ps;
    redn[tid >> 6] = ns;
  }
  __syncthreads();
  if (tid == 0) {
    float tp = redp[0] + redp[1] + redp[2] + redp[3];
    float tn = redn[0] + redn[1] + redn[2] + redn[3];
    rowloss[i] = log1pf(tp) * (1.0f / SCALE_POS) + log1pf(tn) * (1.0f / SCALE_NEG);
  }
}

// ---------------------------------------------------------------------------
// K5: mean over rows. Single block.
__global__ __launch_bounds__(1024) void k5_final(
    const float* __restrict__ rowloss, float* __restrict__ out) {
  int tid = threadIdx.x;
  float local = 0.0f;
  for (int r = tid; r < NB; r += 1024) local += rowloss[r];
#pragma unroll
  for (int d = 1; d < 64; d <<= 1) local += __shfl_xor(local, d, 64);
  __shared__ float partial[16];
  if ((tid & 63) == 0) partial[tid >> 6] = local;
  __syncthreads();
  if (tid == 0) {
    float t = 0.0f;
#pragma unroll
    for (int q = 0; q < 16; ++q) t += partial[q];
    out[0] = t / (float)NB;
  }
}

// ---------------------------------------------------------------------------
extern "C" void kernel_launch(void* const* d_in, const int* in_sizes, int n_in,
                              void* d_out, int out_size, void* d_ws, size_t ws_size,
                              hipStream_t stream) {
  const float* emb = (const float*)d_in[0];
  const int* labels = (const int*)d_in[1];
  float* out = (float*)d_out;
  char* ws = (char*)d_ws;

  short* simh = (short*)ws;                               // 32 MB bf16 sim
  short* F = (short*)(ws + ((size_t)NB * NB * 2));        // 2 MB split-bf16 frags
  char* base = ws + ((size_t)NB * NB * 2) + (2 << 20);
  float* rowloss = (float*)(base);                        // 16 KB
  u8* labu8 = (u8*)(base + 16384);                        // 4 KB

  hipLaunchKernelGGL(k1_convert, dim3(256), dim3(256), 0, stream,
                     emb, labels, F, labu8);
  hipLaunchKernelGGL(k2_pass1, dim3(NB / 128, NB / 128), dim3(256), 0, stream,
                     F, simh);
  hipLaunchKernelGGL(k4_row, dim3(NB), dim3(256), 0, stream,
                     simh, labu8, rowloss);
  hipLaunchKernelGGL(k5_final, dim3(1), dim3(1024), 0, stream, rowloss, out);
}